// Round 10
// baseline (51.089 us; speedup 1.0000x reference)
//
#include <hip/hip_runtime.h>
#include <hip/hip_bf16.h>
#include <math.h>

// Problem constants: B=16, C=64, H=W=64, M=4096
#define KS 16
#define CHUNK 256
#define PART_STRIDE 4224              // 4096 S + 64 rsum + 1 T + pad
#define CTRL_OFF (256 * PART_STRIDE)  // float index of control area in ws
#define S_OFF (CTRL_OFF + 1024)       // float index of s_area

typedef __attribute__((ext_vector_type(8))) short short8;
typedef __attribute__((ext_vector_type(4))) float floatx4;

__device__ __forceinline__ unsigned short f2bf(float f) {
    __hip_bfloat16 h = __float2bfloat16(f);
    return *reinterpret_cast<unsigned short*>(&h);
}
__device__ __forceinline__ float bf2f(unsigned short h) {
    return __uint_as_float(((unsigned int)h) << 16);
}
// Halfword base of element (r, k=8*kb) in the swizzled fragment layout.
__device__ __forceinline__ int HW(int r, int kb) {
    return ((kb << 6) + (r ^ (kb & 15))) << 3;
}
__device__ __forceinline__ floatx4 mfma_bf16(short8 a, short8 b, floatx4 c) {
    return __builtin_amdgcn_mfma_f32_16x16x32_bf16(a, b, c, 0, 0, 0);
}
// Agent-scope (coherence-point) scalar store/load: visible cross-XCD without
// any fence once the issuing wave's vmcnt drains (empirically validated r8).
__device__ __forceinline__ void stA(float* p, float v) {
    __hip_atomic_store(p, v, __ATOMIC_RELAXED, __HIP_MEMORY_SCOPE_AGENT);
}
__device__ __forceinline__ float ldA(const float* p) {
    return __hip_atomic_load(p, __ATOMIC_RELAXED, __HIP_MEMORY_SCOPE_AGENT);
}

// ---------------------------------------------------------------------------
// NS pass helpers, 16 waves (1024 thr). Stored matrices are transposed
// products (valid: all NS iterates symmetric). MODE 0: D=0.5*(3I-P)  1: D=P
// ---------------------------------------------------------------------------
template <int MODE>
__device__ __forceinline__ void pass_single(const unsigned short (*U)[4096],
                                            const unsigned short (*V)[4096],
                                            unsigned short (*D)[4096], int tid) {
    int lane = tid & 63, wv = tid >> 6;
    int g = lane >> 4, rh = lane & 15;
    int ta = wv & 3, tc = wv >> 2;
    floatx4 acc = (floatx4){0.f, 0.f, 0.f, 0.f};
    #pragma unroll
    for (int ks_ = 0; ks_ < 2; ++ks_) {
        int kb = ks_ * 4 + g;
        int ao = HW(16 * ta + rh, kb);
        int bo = HW(16 * tc + rh, kb);
        short8 auh = *reinterpret_cast<const short8*>(&U[0][ao]);
        short8 aul = *reinterpret_cast<const short8*>(&U[1][ao]);
        short8 bvh = *reinterpret_cast<const short8*>(&V[0][bo]);
        short8 bvl = *reinterpret_cast<const short8*>(&V[1][bo]);
        acc = mfma_bf16(auh, bvh, acc);
        acc = mfma_bf16(auh, bvl, acc);
        acc = mfma_bf16(aul, bvh, acc);
    }
    int j = 16 * tc + rh;
    int kbi = 2 * ta + (g >> 1), sub = (g & 1) << 2;
    unsigned short hs[4], ls[4];
    #pragma unroll
    for (int qq = 0; qq < 4; ++qq) {
        int i = 16 * ta + 4 * g + qq;
        float v = acc[qq];
        if (MODE == 0) v = 0.5f * ((i == j ? 3.0f : 0.0f) - v);
        hs[qq] = f2bf(v);
        ls[qq] = f2bf(v - bf2f(hs[qq]));
    }
    int idx = HW(j, kbi) + sub;   // transposed position (j, i)
    uint2 u;
    u.x = hs[0] | ((unsigned)hs[1] << 16); u.y = hs[2] | ((unsigned)hs[3] << 16);
    *reinterpret_cast<uint2*>(&D[0][idx]) = u;
    u.x = ls[0] | ((unsigned)ls[1] << 16); u.y = ls[2] | ((unsigned)ls[3] << 16);
    *reinterpret_cast<uint2*>(&D[1][idx]) = u;
    __syncthreads();
}

// Fused dual pass: waves 0-7 compute DY = Y@W, waves 8-15 compute DZ = W@Z.
__device__ __forceinline__ void pass_fused(const unsigned short (*Y)[4096],
                                           const unsigned short (*W)[4096],
                                           const unsigned short (*Z)[4096],
                                           unsigned short (*DY)[4096],
                                           unsigned short (*DZ)[4096], int tid) {
    int lane = tid & 63, wv = tid >> 6;
    int g = lane >> 4, rh = lane & 15;
    const unsigned short (*U)[4096] = (wv < 8) ? Y : W;
    const unsigned short (*V)[4096] = (wv < 8) ? W : Z;
    unsigned short (*D)[4096] = (wv < 8) ? DY : DZ;
    int w8 = wv & 7;
    int ta0 = (w8 >> 2) << 1, tc = w8 & 3;
    floatx4 acc[2] = {(floatx4){0.f,0.f,0.f,0.f}, (floatx4){0.f,0.f,0.f,0.f}};
    #pragma unroll
    for (int ks_ = 0; ks_ < 2; ++ks_) {
        int kb = ks_ * 4 + g;
        int bo = HW(16 * tc + rh, kb);
        short8 bvh = *reinterpret_cast<const short8*>(&V[0][bo]);
        short8 bvl = *reinterpret_cast<const short8*>(&V[1][bo]);
        #pragma unroll
        for (int a = 0; a < 2; ++a) {
            int ao = HW(16 * (ta0 + a) + rh, kb);
            short8 auh = *reinterpret_cast<const short8*>(&U[0][ao]);
            short8 aul = *reinterpret_cast<const short8*>(&U[1][ao]);
            acc[a] = mfma_bf16(auh, bvh, acc[a]);
            acc[a] = mfma_bf16(auh, bvl, acc[a]);
            acc[a] = mfma_bf16(aul, bvh, acc[a]);
        }
    }
    int j = 16 * tc + rh;
    #pragma unroll
    for (int a = 0; a < 2; ++a) {
        int ta = ta0 + a;
        int kbi = 2 * ta + (g >> 1), sub = (g & 1) << 2;
        unsigned short hs[4], ls[4];
        #pragma unroll
        for (int qq = 0; qq < 4; ++qq) {
            float v = acc[a][qq];
            hs[qq] = f2bf(v);
            ls[qq] = f2bf(v - bf2f(hs[qq]));
        }
        int idx = HW(j, kbi) + sub;
        uint2 u;
        u.x = hs[0] | ((unsigned)hs[1] << 16); u.y = hs[2] | ((unsigned)hs[3] << 16);
        *reinterpret_cast<uint2*>(&D[0][idx]) = u;
        u.x = ls[0] | ((unsigned)ls[1] << 16); u.y = ls[2] | ((unsigned)ls[3] << 16);
        *reinterpret_cast<uint2*>(&D[1][idx]) = u;
    }
    __syncthreads();
}

__device__ __forceinline__ void colsum_stage(const unsigned short (*M)[4096],
                                             float* dst, float* part, int tid) {
    int ii = tid & 63, grp = (tid >> 6) & 7;
    if (tid < 512) {
        int o = HW(ii, grp);
        short8 vh = *reinterpret_cast<const short8*>(&M[0][o]);
        short8 vl = *reinterpret_cast<const short8*>(&M[1][o]);
        float s = 0.f;
        #pragma unroll
        for (int e = 0; e < 8; ++e)
            s += bf2f((unsigned short)vh[e]) + bf2f((unsigned short)vl[e]);
        part[grp * 64 + ii] = s;
    }
    __syncthreads();
    if (tid < 64) {
        float s = 0.f;
        #pragma unroll
        for (int q = 0; q < 8; ++q) s += part[q * 64 + tid];
        dst[tid] = s;
    }
    __syncthreads();
}

__device__ __forceinline__ void matvec_stage(const unsigned short (*M)[4096],
                                             const float* __restrict__ src,
                                             float* dst, float* part, int tid) {
    int ii = tid & 63, grp = (tid >> 6) & 7;
    if (tid < 512) {
        int o = HW(ii, grp);
        short8 vh = *reinterpret_cast<const short8*>(&M[0][o]);
        short8 vl = *reinterpret_cast<const short8*>(&M[1][o]);
        float s = 0.f;
        #pragma unroll
        for (int e = 0; e < 8; ++e)
            s += (bf2f((unsigned short)vh[e]) + bf2f((unsigned short)vl[e])) * src[grp * 8 + e];
        part[grp * 64 + ii] = s;
    }
    __syncthreads();
    if (tid < 64) {
        float s = 0.f;
        #pragma unroll
        for (int q = 0; q < 8; ++q) s += part[q * 64 + tid];
        dst[tid] = s;
    }
    __syncthreads();
}

// ---------------------------------------------------------------------------
// K1: Gram partials written via agent-scope (coherence-point) stores -> NO
// fences anywhere. Election: vmcnt drained by __syncthreads, then relaxed
// agent atomicAdd. Finisher reads partials via agent-scope loads.
// ---------------------------------------------------------------------------
__global__ __launch_bounds__(1024, 1) void soca_main(const float* __restrict__ x,
                                                     const float* __restrict__ w1,
                                                     const float* __restrict__ b1,
                                                     const float* __restrict__ w2,
                                                     const float* __restrict__ b2,
                                                     float* __restrict__ ws) {
    __shared__ __align__(16) unsigned char big[81920];   // A: xh/xl/csp  C: planes
    __shared__ __align__(16) float auxf[1024];
    __shared__ float w1t[4096];   // taps [i][o]
    __shared__ float w2t[4096];
    __shared__ int isFinSh;
    int bk = blockIdx.x, tid = threadIdx.x;
    int w = tid >> 6, l = tid & 63;
    int b = bk >> 4, ks = bk & 15;
    const float invM = 1.0f / 4096.0f;
    unsigned int* ctrl = (unsigned int*)(ws + CTRL_OFF);  // ctr b at ctrl[b*64]
    float* s_area = ws + S_OFF;
    float* outp = ws + (size_t)bk * PART_STRIDE;

    // ================= Phase A: partial Gram for (b, ks) ====================
    {
        unsigned short* xh = (unsigned short*)big;
        unsigned short* xl = xh + 64 * CHUNK;
        float* cspL = (float*)(big + 65536);   // [16][256] per-wave colsum partials
        const float* xb = x + ((size_t)b * 64) * 4096 + ks * CHUNK;

        float cs0 = 0.f, cs1 = 0.f, cs2 = 0.f, cs3 = 0.f;
        #pragma unroll
        for (int r = 0; r < 4; ++r) {
            int c = w * 4 + r;
            float4 v = *reinterpret_cast<const float4*>(xb + (size_t)c * 4096 + l * 4);
            cs0 += v.x; cs1 += v.y; cs2 += v.z; cs3 += v.w;
            float rsp = v.x + v.y + v.z + v.w;      // row-sum partial, wave covers row
            #pragma unroll
            for (int off = 32; off >= 1; off >>= 1) rsp += __shfl_xor(rsp, off, 64);
            if (l == 0) stA(&outp[4096 + c], rsp);
            float vv[4] = {v.x, v.y, v.z, v.w};
            unsigned short hs[4], ls_[4];
            #pragma unroll
            for (int q = 0; q < 4; ++q) {
                hs[q] = f2bf(vv[q]);
                ls_[q] = f2bf(vv[q] - bf2f(hs[q]));
            }
            int idx = HW(c, l >> 1) + ((l & 1) << 2);
            uint2 u;
            u.x = hs[0] | ((unsigned)hs[1] << 16); u.y = hs[2] | ((unsigned)hs[3] << 16);
            *reinterpret_cast<uint2*>(&xh[idx]) = u;
            u.x = ls_[0] | ((unsigned)ls_[1] << 16); u.y = ls_[2] | ((unsigned)ls_[3] << 16);
            *reinterpret_cast<uint2*>(&xl[idx]) = u;
        }
        *reinterpret_cast<float4*>(&cspL[w * 256 + l * 4]) = make_float4(cs0, cs1, cs2, cs3);
        __syncthreads();

        // MFMA Gram: wave w owns tile (ta, tc)
        int g = l >> 4, rh = l & 15;
        int ta = w >> 2, tc = w & 3;
        floatx4 acc = (floatx4){0.f, 0.f, 0.f, 0.f};
        #pragma unroll
        for (int ks_ = 0; ks_ < 8; ++ks_) {
            int kb = ks_ * 4 + g;
            int ao = HW(16 * ta + rh, kb);
            int bo = HW(16 * tc + rh, kb);
            short8 auh = *reinterpret_cast<const short8*>(&xh[ao]);
            short8 aul = *reinterpret_cast<const short8*>(&xl[ao]);
            short8 bvh = *reinterpret_cast<const short8*>(&xh[bo]);
            short8 bvl = *reinterpret_cast<const short8*>(&xl[bo]);
            acc = mfma_bf16(auh, bvh, acc);
            acc = mfma_bf16(auh, bvl, acc);
            acc = mfma_bf16(aul, bvh, acc);
        }
        {   // store S^T position (S symmetric) via coherence-point stores
            int j = 16 * tc + rh, i0 = 16 * ta + 4 * g;
            float* dp = &outp[j * 64 + i0];
            #pragma unroll
            for (int q = 0; q < 4; ++q) stA(dp + q, acc[q]);
        }
        // T partial = sum_m colsum_m^2
        float* red = auxf;
        if (tid < 256) {
            float cm = 0.f;
            #pragma unroll
            for (int ww = 0; ww < 16; ++ww) cm += cspL[ww * 256 + tid];
            red[tid] = cm * cm;
        }
        __syncthreads();
        for (int st = 128; st > 0; st >>= 1) {
            if (tid < st) red[tid] += red[tid + st];
            __syncthreads();
        }
        if (tid == 0) stA(&outp[4160], red[0]);
    }

    // ================= Finisher election (no fences) ========================
    __syncthreads();   // drains vmcnt -> all agent-scope stores are visible
    if (tid == 0) {
        unsigned int old = __hip_atomic_fetch_add(&ctrl[b * 64], 1u,
                                                  __ATOMIC_RELAXED, __HIP_MEMORY_SCOPE_AGENT);
        isFinSh = (old == 15u) ? 1 : 0;
    }
    __syncthreads();
    if (!isFinSh) return;   // non-finishers exit; kernel boundary does the rest

    // ================= Phase C (finisher only): reduce + NS + conv ==========
    {
        // stage conv center taps [i][o] into LDS with all 1024 threads
        #pragma unroll
        for (int t = tid; t < 4096; t += 1024) {
            int i = t >> 6, o = t & 63;
            w1t[t] = w1[(o * 64 + i) * 9 + 4];
            w2t[t] = w2[(o * 64 + i) * 9 + 4];
        }
    }
    unsigned short (*planes)[2][4096] = (unsigned short (*)[2][4096])big;
    const float* base = ws + (size_t)b * KS * PART_STRIDE;
    float* rsumL = auxf;   // [64]; auxf[64]=T, auxf[65]=normA

    if (tid < 64) {
        float s = 0.f;
        for (int k = 0; k < KS; ++k) s += ldA(base + k * PART_STRIDE + 4096 + tid);
        rsumL[tid] = s;
    } else if (tid == 64) {
        float t = 0.f;
        for (int k = 0; k < KS; ++k) t += ldA(base + k * PART_STRIDE + 4160);
        auxf[64] = t;
    }
    int e = tid * 4;
    int i = tid >> 4, j0 = (tid & 15) * 4;
    floatx4 s4 = (floatx4){0.f, 0.f, 0.f, 0.f};
    for (int k = 0; k < KS; ++k) {
        const float* pp = base + k * PART_STRIDE + e;
        s4[0] += ldA(pp + 0);
        s4[1] += ldA(pp + 1);
        s4[2] += ldA(pp + 2);
        s4[3] += ldA(pp + 3);
    }
    __syncthreads();
    if (tid == 0) {
        float sr = 0.f;
        for (int q = 0; q < 64; ++q) sr += rsumL[q];
        auxf[65] = (auxf[64] - sr * sr * invM) * invM;   // normA = sum_ij cov
    }
    __syncthreads();
    float normA = auxf[65];
    float invNA = 1.0f / normA;
    float mui = rsumL[i] * invM;
    unsigned short ah[4], al_[4], zh[4], zl[4];
    #pragma unroll
    for (int q = 0; q < 4; ++q) {
        float cv = s4[q] * invM - mui * (rsumL[j0 + q] * invM);
        float a = cv * invNA;
        float z = 0.5f * (((i == j0 + q) ? 3.0f : 0.0f) - a);
        unsigned short h = f2bf(a);
        ah[q] = h; al_[q] = f2bf(a - bf2f(h));
        h = f2bf(z);
        zh[q] = h; zl[q] = f2bf(z - bf2f(h));
    }
    {
        int idx = HW(i, j0 >> 3) + (j0 & 7);
        uint2 u;
        u.x = ah[0] | ((unsigned)ah[1] << 16); u.y = ah[2] | ((unsigned)ah[3] << 16);
        *reinterpret_cast<uint2*>(&planes[0][0][idx]) = u;
        u.x = al_[0] | ((unsigned)al_[1] << 16); u.y = al_[2] | ((unsigned)al_[3] << 16);
        *reinterpret_cast<uint2*>(&planes[0][1][idx]) = u;
        u.x = zh[0] | ((unsigned)zh[1] << 16); u.y = zh[2] | ((unsigned)zh[3] << 16);
        *reinterpret_cast<uint2*>(&planes[1][0][idx]) = u;
        u.x = zl[0] | ((unsigned)zl[1] << 16); u.y = zl[2] | ((unsigned)zl[3] << 16);
        *reinterpret_cast<uint2*>(&planes[1][1][idx]) = u;
    }
    __syncthreads();

    // NS: Y0 = A@Z0; 3x {W=.5(3I-ZY); Y=YW; Z=WZ} with last Z skipped
    pass_single<1>(planes[0], planes[1], planes[2], tid);   // Y0 -> s2
    pass_single<0>(planes[1], planes[2], planes[0], tid);   // W1 -> s0
    pass_fused(planes[2], planes[0], planes[1], planes[3], planes[4], tid); // Y1->s3,Z1->s4
    pass_single<0>(planes[4], planes[3], planes[1], tid);   // W2 -> s1
    pass_fused(planes[3], planes[1], planes[4], planes[2], planes[0], tid); // Y2->s2,Z2->s0
    pass_single<0>(planes[0], planes[2], planes[3], tid);   // W3 -> s3
    pass_single<1>(planes[2], planes[3], planes[4], tid);   // Y3 -> s4

    // Epilogue: r = 3u - Y3(W3(Z2 u)), u = colsum(Y3)
    float* part = auxf;          // 512 (rsumL dead now)
    float* uvec = auxf + 512;
    float* avec = auxf + 576;
    float* pvec = auxf + 640;
    float* wvec = auxf + 704;
    float* ych  = auxf + 768;
    float* hid  = auxf + 832;
    colsum_stage(planes[4], uvec, part, tid);
    matvec_stage(planes[0], uvec, avec, part, tid);   // a = Z2 u
    matvec_stage(planes[3], avec, pvec, part, tid);   // p = W3 a
    matvec_stage(planes[4], pvec, wvec, part, tid);   // w = Y3 p

    if (tid < 64)
        ych[tid] = (3.0f * uvec[tid] - wvec[tid]) * (0.5f / 64.0f) * sqrtf(normA);
    __syncthreads();
    if (tid < 64) {
        float t1 = b1[tid];
        for (int ii = 0; ii < 64; ++ii) t1 += w1t[ii * 64 + tid] * ych[ii];
        hid[tid] = fmaxf(t1, 0.f);
    }
    __syncthreads();
    if (tid < 64) {
        float t2 = b2[tid];
        for (int ii = 0; ii < 64; ++ii) t2 += w2t[ii * 64 + tid] * hid[ii];
        s_area[b * 64 + tid] = 1.0f / (1.0f + expf(-t2));   // kernel boundary publishes
    }
}

// ---------------------------------------------------------------------------
// K2: out[b,c,h,w] = s[b,c] * x[b,c,h,w], float4 grid-stride
// ---------------------------------------------------------------------------
__global__ __launch_bounds__(256) void scale_kernel(const float* __restrict__ x,
                                                    const float* __restrict__ s,
                                                    float* __restrict__ out, int n4) {
    int idx = blockIdx.x * 256 + threadIdx.x;
    int stride = gridDim.x * 256;
    for (int f = idx; f < n4; f += stride) {
        float sv = s[f >> 10];
        float4 v = reinterpret_cast<const float4*>(x)[f];
        reinterpret_cast<float4*>(out)[f] = make_float4(v.x * sv, v.y * sv, v.z * sv, v.w * sv);
    }
}

extern "C" void kernel_launch(void* const* d_in, const int* in_sizes, int n_in,
                              void* d_out, int out_size, void* d_ws, size_t ws_size,
                              hipStream_t stream) {
    const float* x  = (const float*)d_in[0];
    const float* w1 = (const float*)d_in[1];
    const float* b1 = (const float*)d_in[2];
    const float* w2 = (const float*)d_in[3];
    const float* b2 = (const float*)d_in[4];
    float* out = (float*)d_out;
    float* ws  = (float*)d_ws;

    // Zero the election counters.
    (void)hipMemsetAsync(ws + CTRL_OFF, 0, 4096, stream);
    soca_main<<<dim3(256), dim3(1024), 0, stream>>>(x, w1, b1, w2, b2, ws);
    scale_kernel<<<dim3(2048), dim3(256), 0, stream>>>(x, ws + S_OFF, out, 1048576);
}

// Round 11
// 50.426 us; speedup vs baseline: 1.0132x; 1.0132x over previous
//
#include <hip/hip_runtime.h>
#include <hip/hip_bf16.h>
#include <math.h>

// Problem constants: B=16, C=64, H=W=64, M=4096
#define KS 16
#define CHUNK 256
#define PART_STRIDE 4224   // 4096 S + 64 rsum + 1 T + pad (divisible by 4)

typedef __attribute__((ext_vector_type(8))) short short8;
typedef __attribute__((ext_vector_type(4))) float floatx4;

__device__ __forceinline__ unsigned short f2bf(float f) {
    __hip_bfloat16 h = __float2bfloat16(f);
    return *reinterpret_cast<unsigned short*>(&h);
}
__device__ __forceinline__ float bf2f(unsigned short h) {
    return __uint_as_float(((unsigned int)h) << 16);
}
// Halfword base of element (r, k=8*kb) in the swizzled fragment layout.
__device__ __forceinline__ int HW(int r, int kb) {
    return ((kb << 6) + (r ^ (kb & 15))) << 3;
}
__device__ __forceinline__ floatx4 mfma_bf16(short8 a, short8 b, floatx4 c) {
    return __builtin_amdgcn_mfma_f32_16x16x32_bf16(a, b, c, 0, 0, 0);
}

// ---------------------------------------------------------------------------
// K1: per-(batch,chunk) partial Gram via MFMA + partial rowsums + partial
// T = sum_m (colsum_m)^2. 256 blocks x 256 threads. (Proven round 3/4.)
// ---------------------------------------------------------------------------
__global__ __launch_bounds__(256) void cov_partial_kernel(const float* __restrict__ x,
                                                          float* __restrict__ ws) {
    __shared__ __align__(16) unsigned short xh[64 * CHUNK];
    __shared__ __align__(16) unsigned short xl[64 * CHUNK];
    __shared__ float rs_part[4][64];
    __shared__ float csp[4][256];
    __shared__ float red[256];
    int blk = blockIdx.x, b = blk >> 4, ks = blk & 15;
    int tid = threadIdx.x, lane = tid & 63, wv = tid >> 6;
    const float* xb = x + ((size_t)b * 64) * 4096 + ks * CHUNK;

    int kbw = lane >> 1, wsub = (lane & 1) << 2;
    float cs0 = 0.f, cs1 = 0.f, cs2 = 0.f, cs3 = 0.f;
    #pragma unroll
    for (int r = 0; r < 16; ++r) {
        int c = wv * 16 + r;
        float4 v = *reinterpret_cast<const float4*>(xb + (size_t)c * 4096 + lane * 4);
        cs0 += v.x; cs1 += v.y; cs2 += v.z; cs3 += v.w;
        float vv[4] = {v.x, v.y, v.z, v.w};
        unsigned short hs[4], ls[4];
        #pragma unroll
        for (int q = 0; q < 4; ++q) {
            hs[q] = f2bf(vv[q]);
            ls[q] = f2bf(vv[q] - bf2f(hs[q]));
        }
        int idx = HW(c, kbw) + wsub;
        uint2 u;
        u.x = hs[0] | ((unsigned)hs[1] << 16); u.y = hs[2] | ((unsigned)hs[3] << 16);
        *reinterpret_cast<uint2*>(&xh[idx]) = u;
        u.x = ls[0] | ((unsigned)ls[1] << 16); u.y = ls[2] | ((unsigned)ls[3] << 16);
        *reinterpret_cast<uint2*>(&xl[idx]) = u;
    }
    *reinterpret_cast<float4*>(&csp[wv][lane * 4]) = make_float4(cs0, cs1, cs2, cs3);
    __syncthreads();

    float cm = csp[0][tid] + csp[1][tid] + csp[2][tid] + csp[3][tid];

    int g = lane >> 4, rh = lane & 15;
    int ta0 = (wv >> 1) << 1, tc0 = (wv & 1) << 1;
    floatx4 acc[2][2];
    #pragma unroll
    for (int a = 0; a < 2; ++a)
        #pragma unroll
        for (int c = 0; c < 2; ++c)
            acc[a][c] = (floatx4){0.f, 0.f, 0.f, 0.f};

    #pragma unroll
    for (int ks_ = 0; ks_ < 8; ++ks_) {
        int kb = ks_ * 4 + g;
        short8 ah[2], al[2], bh[2], bl[2];
        #pragma unroll
        for (int a = 0; a < 2; ++a) {
            int o = HW(16 * (ta0 + a) + rh, kb);
            ah[a] = *reinterpret_cast<const short8*>(&xh[o]);
            al[a] = *reinterpret_cast<const short8*>(&xl[o]);
        }
        #pragma unroll
        for (int c = 0; c < 2; ++c) {
            int o = HW(16 * (tc0 + c) + rh, kb);
            bh[c] = *reinterpret_cast<const short8*>(&xh[o]);
            bl[c] = *reinterpret_cast<const short8*>(&xl[o]);
        }
        #pragma unroll
        for (int a = 0; a < 2; ++a)
            #pragma unroll
            for (int c = 0; c < 2; ++c) {
                acc[a][c] = mfma_bf16(ah[a], bh[c], acc[a][c]);
                acc[a][c] = mfma_bf16(ah[a], bl[c], acc[a][c]);
                acc[a][c] = mfma_bf16(al[a], bh[c], acc[a][c]);
            }
    }

    float* outp = ws + (size_t)blk * PART_STRIDE;
    #pragma unroll
    for (int a = 0; a < 2; ++a)
        #pragma unroll
        for (int c = 0; c < 2; ++c) {
            int j = 16 * (tc0 + c) + rh;
            int i0 = 16 * (ta0 + a) + 4 * g;
            *reinterpret_cast<float4*>(&outp[j * 64 + i0]) =
                make_float4(acc[a][c][0], acc[a][c][1], acc[a][c][2], acc[a][c][3]);
        }

    {   // partial row sums from staged planes (hi+lo ~ fp32)
        float s = 0.f;
        #pragma unroll
        for (int m = 0; m < 8; ++m) {
            int o = HW(lane, wv * 8 + m);
            short8 vh = *reinterpret_cast<const short8*>(&xh[o]);
            short8 vl = *reinterpret_cast<const short8*>(&xl[o]);
            #pragma unroll
            for (int e = 0; e < 8; ++e)
                s += bf2f((unsigned short)vh[e]) + bf2f((unsigned short)vl[e]);
        }
        rs_part[wv][lane] = s;
    }
    red[tid] = cm * cm;
    __syncthreads();
    for (int st = 128; st > 0; st >>= 1) {
        if (tid < st) red[tid] += red[tid + st];
        __syncthreads();
    }
    if (tid < 64)
        outp[4096 + tid] = rs_part[0][tid] + rs_part[1][tid] + rs_part[2][tid] + rs_part[3][tid];
    if (tid == 0) outp[4160] = red[0];
}

// ---------------------------------------------------------------------------
// Single-wave 64x64x64 split-bf16 matmul pass. One wave computes all 16
// 16x16 tiles; no inter-wave barriers exist (block = 1 wave).
// Stored matrices are transposed products (all NS iterates symmetric).
// MODE 0: D = 0.5*(3I - P)   MODE 1: D = P
// ---------------------------------------------------------------------------
template <int MODE>
__device__ __forceinline__ void mm64w(const unsigned short (*U)[4096],
                                      const unsigned short (*V)[4096],
                                      unsigned short (*D)[4096], int lane) {
    int g = lane >> 4, rh = lane & 15;
    floatx4 acc[4][4];
    #pragma unroll
    for (int a = 0; a < 4; ++a)
        #pragma unroll
        for (int c = 0; c < 4; ++c)
            acc[a][c] = (floatx4){0.f, 0.f, 0.f, 0.f};

    #pragma unroll
    for (int ks_ = 0; ks_ < 2; ++ks_) {
        int kb = ks_ * 4 + g;
        short8 uh[4], ul[4], vh[4], vl[4];
        #pragma unroll
        for (int a = 0; a < 4; ++a) {
            int o = HW(16 * a + rh, kb);
            uh[a] = *reinterpret_cast<const short8*>(&U[0][o]);
            ul[a] = *reinterpret_cast<const short8*>(&U[1][o]);
        }
        #pragma unroll
        for (int c = 0; c < 4; ++c) {
            int o = HW(16 * c + rh, kb);
            vh[c] = *reinterpret_cast<const short8*>(&V[0][o]);
            vl[c] = *reinterpret_cast<const short8*>(&V[1][o]);
        }
        #pragma unroll
        for (int a = 0; a < 4; ++a)
            #pragma unroll
            for (int c = 0; c < 4; ++c) {
                acc[a][c] = mfma_bf16(uh[a], vh[c], acc[a][c]);
                acc[a][c] = mfma_bf16(uh[a], vl[c], acc[a][c]);
                acc[a][c] = mfma_bf16(ul[a], vh[c], acc[a][c]);
            }
    }

    #pragma unroll
    for (int a = 0; a < 4; ++a) {
        int kbi = 2 * a + (g >> 1), sub = (g & 1) << 2;
        #pragma unroll
        for (int c = 0; c < 4; ++c) {
            int j = 16 * c + rh;
            unsigned short hs[4], ls[4];
            #pragma unroll
            for (int qq = 0; qq < 4; ++qq) {
                int i = 16 * a + 4 * g + qq;
                float v = acc[a][c][qq];
                if (MODE == 0) v = 0.5f * ((i == j ? 3.0f : 0.0f) - v);
                hs[qq] = f2bf(v);
                ls[qq] = f2bf(v - bf2f(hs[qq]));
            }
            int idx = HW(j, kbi) + sub;   // transposed position (j, i)
            uint2 u;
            u.x = hs[0] | ((unsigned)hs[1] << 16); u.y = hs[2] | ((unsigned)hs[3] << 16);
            *reinterpret_cast<uint2*>(&D[0][idx]) = u;
            u.x = ls[0] | ((unsigned)ls[1] << 16); u.y = ls[2] | ((unsigned)ls[3] << 16);
            *reinterpret_cast<uint2*>(&D[1][idx]) = u;
        }
    }
    __syncthreads();   // 1-wave block: compiles to waitcnt, orders LDS w->r
}

// Single-wave matvec dst_i = sum_j M[i][j] src[j] (M symmetric; stored rows
// of the transposed layout == actual rows).
__device__ __forceinline__ float mv64(const unsigned short (*M)[4096],
                                      const float* __restrict__ src, int lane) {
    float s = 0.f;
    #pragma unroll
    for (int kb = 0; kb < 8; ++kb) {
        int o = HW(lane, kb);
        short8 vh = *reinterpret_cast<const short8*>(&M[0][o]);
        short8 vl = *reinterpret_cast<const short8*>(&M[1][o]);
        #pragma unroll
        for (int e = 0; e < 8; ++e)
            s += (bf2f((unsigned short)vh[e]) + bf2f((unsigned short)vl[e])) * src[kb * 8 + e];
    }
    return s;
}

// ---------------------------------------------------------------------------
// K2: one WAVE per batch (16 blocks x 64 threads). Reduce partials ->
// cov -> A,Z0 planes -> 9 single-wave MFMA passes -> matvec epilogue ->
// conv chain -> sigmoid scales.
// ---------------------------------------------------------------------------
__global__ __launch_bounds__(64, 1) void ns64_kernel(const float* __restrict__ wsin,
                                                     const float* __restrict__ w1,
                                                     const float* __restrict__ b1,
                                                     const float* __restrict__ w2,
                                                     const float* __restrict__ b2,
                                                     float* __restrict__ s_out) {
    __shared__ __align__(16) unsigned short planes[5][2][4096];  // 80 KB
    __shared__ float rsum[64], uvec[64], avec[64], pvec[64], ych[64], hid[64];
    int b = blockIdx.x, lane = threadIdx.x;
    const float invM = 1.0f / 4096.0f;
    const float* base = wsin + (size_t)b * KS * PART_STRIDE;

    // rowsums + T + normA (wave-local)
    float rs = 0.f;
    for (int k = 0; k < KS; ++k) rs += base[k * PART_STRIDE + 4096 + lane];
    rsum[lane] = rs;
    float sr = rs;
    #pragma unroll
    for (int off = 32; off >= 1; off >>= 1) sr += __shfl_xor(sr, off, 64);
    float T = 0.f;
    for (int k = 0; k < KS; ++k) T += base[k * PART_STRIDE + 4160];
    const float normA = (T - sr * sr * invM) * invM;
    const float invNA = 1.0f / normA;
    __syncthreads();

    // reduce split-K S + center + convert to A (slot0), Z0 (slot1)
    const floatx4* b4 = reinterpret_cast<const floatx4*>(base);
    #pragma unroll
    for (int chunk = 0; chunk < 16; ++chunk) {
        int t = chunk * 64 + lane;
        floatx4 s4 = (floatx4){0.f, 0.f, 0.f, 0.f};
        for (int k = 0; k < KS; ++k) s4 += b4[k * (PART_STRIDE / 4) + t];
        int i = t >> 4, j0 = (t & 15) * 4;
        float mui = rsum[i] * invM;
        unsigned short ah[4], al_[4], zh[4], zl[4];
        #pragma unroll
        for (int q = 0; q < 4; ++q) {
            float cv = s4[q] * invM - mui * (rsum[j0 + q] * invM);
            float a = cv * invNA;
            float z = 0.5f * (((i == j0 + q) ? 3.0f : 0.0f) - a);
            unsigned short h = f2bf(a);
            ah[q] = h; al_[q] = f2bf(a - bf2f(h));
            h = f2bf(z);
            zh[q] = h; zl[q] = f2bf(z - bf2f(h));
        }
        int idx = HW(i, j0 >> 3) + (j0 & 7);
        uint2 u;
        u.x = ah[0] | ((unsigned)ah[1] << 16); u.y = ah[2] | ((unsigned)ah[3] << 16);
        *reinterpret_cast<uint2*>(&planes[0][0][idx]) = u;
        u.x = al_[0] | ((unsigned)al_[1] << 16); u.y = al_[2] | ((unsigned)al_[3] << 16);
        *reinterpret_cast<uint2*>(&planes[0][1][idx]) = u;
        u.x = zh[0] | ((unsigned)zh[1] << 16); u.y = zh[2] | ((unsigned)zh[3] << 16);
        *reinterpret_cast<uint2*>(&planes[1][0][idx]) = u;
        u.x = zl[0] | ((unsigned)zl[1] << 16); u.y = zl[2] | ((unsigned)zl[3] << 16);
        *reinterpret_cast<uint2*>(&planes[1][1][idx]) = u;
    }
    __syncthreads();

    // NS chain (slot trace verified against round-4 sequence):
    mm64w<1>(planes[0], planes[1], planes[2], lane);   // Y0 = A@Z0    -> s2
    mm64w<0>(planes[1], planes[2], planes[0], lane);   // W1           -> s0
    mm64w<1>(planes[2], planes[0], planes[3], lane);   // Y1 = Y0@W1   -> s3
    mm64w<1>(planes[0], planes[1], planes[4], lane);   // Z1 = W1@Z0   -> s4
    mm64w<0>(planes[4], planes[3], planes[1], lane);   // W2           -> s1
    mm64w<1>(planes[3], planes[1], planes[2], lane);   // Y2 = Y1@W2   -> s2
    mm64w<1>(planes[1], planes[4], planes[0], lane);   // Z2 = W2@Z1   -> s0
    mm64w<0>(planes[0], planes[2], planes[3], lane);   // W3           -> s3
    mm64w<1>(planes[2], planes[3], planes[4], lane);   // Y3 = Y2@W3   -> s4

    // Epilogue: r = 3u - Y3(W3(Z2 u)), u = colsum(Y3)
    {
        float s = 0.f;
        #pragma unroll
        for (int kb = 0; kb < 8; ++kb) {
            int o = HW(lane, kb);
            short8 vh = *reinterpret_cast<const short8*>(&planes[4][0][o]);
            short8 vl = *reinterpret_cast<const short8*>(&planes[4][1][o]);
            #pragma unroll
            for (int e = 0; e < 8; ++e)
                s += bf2f((unsigned short)vh[e]) + bf2f((unsigned short)vl[e]);
        }
        uvec[lane] = s;
    }
    __syncthreads();
    avec[lane] = mv64(planes[0], uvec, lane);   // a = Z2 u
    __syncthreads();
    pvec[lane] = mv64(planes[3], avec, lane);   // p = W3 a
    __syncthreads();
    float wv_ = mv64(planes[4], pvec, lane);    // w = Y3 p
    ych[lane] = (3.0f * uvec[lane] - wv_) * (0.5f / 64.0f) * sqrtf(normA);
    __syncthreads();

    // conv-relu-conv-sigmoid (center taps read straight from global)
    float t1 = b1[lane];
    for (int i2 = 0; i2 < 64; ++i2)
        t1 += w1[(lane * 64 + i2) * 9 + 4] * ych[i2];
    hid[lane] = fmaxf(t1, 0.f);
    __syncthreads();
    float t2 = b2[lane];
    for (int i2 = 0; i2 < 64; ++i2)
        t2 += w2[(lane * 64 + i2) * 9 + 4] * hid[i2];
    s_out[b * 64 + lane] = 1.0f / (1.0f + expf(-t2));
}

// ---------------------------------------------------------------------------
// K3: out[b,c,h,w] = s[b,c] * x[b,c,h,w], float4 grid-stride
// ---------------------------------------------------------------------------
__global__ __launch_bounds__(256) void scale_kernel(const float* __restrict__ x,
                                                    const float* __restrict__ s,
                                                    float* __restrict__ out, int n4) {
    int idx = blockIdx.x * 256 + threadIdx.x;
    int stride = gridDim.x * 256;
    for (int f = idx; f < n4; f += stride) {
        float sv = s[f >> 10];
        float4 v = reinterpret_cast<const float4*>(x)[f];
        reinterpret_cast<float4*>(out)[f] = make_float4(v.x * sv, v.y * sv, v.z * sv, v.w * sv);
    }
}

extern "C" void kernel_launch(void* const* d_in, const int* in_sizes, int n_in,
                              void* d_out, int out_size, void* d_ws, size_t ws_size,
                              hipStream_t stream) {
    const float* x  = (const float*)d_in[0];
    const float* w1 = (const float*)d_in[1];
    const float* b1 = (const float*)d_in[2];
    const float* w2 = (const float*)d_in[3];
    const float* b2 = (const float*)d_in[4];
    float* out = (float*)d_out;
    float* ws  = (float*)d_ws;
    float* s_area = ws + (size_t)256 * PART_STRIDE;

    cov_partial_kernel<<<dim3(256), dim3(256), 0, stream>>>(x, ws);
    ns64_kernel<<<dim3(16), dim3(64), 0, stream>>>(ws, w1, b1, w2, b2, s_area);
    scale_kernel<<<dim3(2048), dim3(256), 0, stream>>>(x, s_area, out, 1048576);
}